// Round 2
// baseline (735.257 us; speedup 1.0000x reference)
//
#include <hip/hip_runtime.h>
#include <math.h>
#include <limits.h>

#define QN 1024
#define NN 50000
#define NPAD 50048        /* 391*128 exactly */
#define DD 512
#define KNN 10
#define NT 128
#define QTB 128
#define BK 32
#define NS 391
#define QB 8
#define NSAMP 31
#define NREST (NS - NSAMP)    /* 360 */
#define CAP 512

/* workspace layout, in 4-byte words */
#define WS_D2  0
#define WS_TAU 50048                       /* u64[1024] */
#define WS_CNT (WS_TAU + 2048)
#define WS_XH  (WS_CNT + 1024)
#define WS_XL  (WS_XH + QN * DD / 2)
#define WS_CKS (WS_XL + QN * DD / 2)       /* u64[QN*NSAMP*KNN] */
#define WS_BUF (WS_CKS + QN * NSAMP * KNN * 2)
#define WS_DH  (WS_BUF + QN * CAP * 2)     /* tiled data hi: 391*16*8192 B */
#define WS_DL  (WS_DH + NS * 16 * 2048)
#define WS_END (WS_DL + NS * 16 * 2048)

typedef __attribute__((ext_vector_type(8))) short short8;
typedef __attribute__((ext_vector_type(4))) float f32x4;
typedef unsigned long long u64;

__device__ __forceinline__ u64 mkkey(float f, int idx) {
  unsigned u = __float_as_uint(f);
  unsigned m = u ^ ((unsigned)((int)u >> 31) | 0x80000000u);
  return ((u64)m << 32) | (unsigned)idx;
}

__device__ __forceinline__ void cvt2(float x, float y, unsigned& hi, unsigned& lo) {
  unsigned ux = __float_as_uint(x), uy = __float_as_uint(y);
  unsigned rx = ux + 0x7fffu + ((ux >> 16) & 1u);
  unsigned ry = uy + 0x7fffu + ((uy >> 16) & 1u);
  hi = (rx >> 16) | (ry & 0xffff0000u);
  float xl = x - __uint_as_float(rx & 0xffff0000u);
  float yl = y - __uint_as_float(ry & 0xffff0000u);
  unsigned uxl = __float_as_uint(xl), uyl = __float_as_uint(yl);
  unsigned rxl = uxl + 0x7fffu + ((uxl >> 16) & 1u);
  unsigned ryl = uyl + 0x7fffu + ((uyl >> 16) & 1u);
  lo = (rxl >> 16) | (ryl & 0xffff0000u);
}

__device__ __forceinline__ void glds16(const void* g, void* l) {
  __builtin_amdgcn_global_load_lds(
      (const __attribute__((address_space(1))) unsigned*)g,
      (__attribute__((address_space(3))) unsigned*)l, 16, 0, 0);
}

__device__ __forceinline__ void ins10(u64* kl, u64 k) {
#pragma unroll
  for (int u = 0; u < KNN; u++) {
    u64 lo = (k < kl[u]) ? k : kl[u];
    u64 hi = (k < kl[u]) ? kl[u] : k;
    kl[u] = lo; k = hi;
  }
}

/* ---------------- K0: preconvert X to split-bf16 row-major -------------- */
__global__ __launch_bounds__(256) void convx_kernel(
    const float* __restrict__ Xm, float* __restrict__ ws) {
  int w = threadIdx.x >> 6, lane = threadIdx.x & 63;
  int row = blockIdx.x * 4 + w;
  const float4* p = (const float4*)(Xm + (size_t)row * DD) + lane * 2;
  float4 v0 = p[0], v1 = p[1];
  unsigned h[4], l[4];
  cvt2(v0.x, v0.y, h[0], l[0]); cvt2(v0.z, v0.w, h[1], l[1]);
  cvt2(v1.x, v1.y, h[2], l[2]); cvt2(v1.z, v1.w, h[3], l[3]);
  ((uint4*)(ws + WS_XH))[row * 64 + lane] = make_uint4(h[0], h[1], h[2], h[3]);
  ((uint4*)(ws + WS_XL))[row * 64 + lane] = make_uint4(l[0], l[1], l[2], l[3]);
}

/* ------- K1: fused data preconvert (tiled split-bf16) + row norms -------
   (r0-proven version, restored verbatim for the bisect) ------------------ */
__global__ __launch_bounds__(256) void convd_kernel(
    const float* __restrict__ dat, float* __restrict__ ws) {
  const int slice = blockIdx.x;
  const int t = threadIdx.x;
  const int row = t >> 1, h2 = t & 1;
  const int gr = slice * NT + row;
  const int r15 = row & 15;
  float s = 0.f;
#pragma unroll
  for (int kc8 = 0; kc8 < 8; kc8++) {
    const int kc = h2 * 8 + kc8;
    float4 v[8];
    if (gr < NN) {
      const float4* src = (const float4*)(dat + (size_t)gr * DD + kc * 32);
#pragma unroll
      for (int j = 0; j < 8; j++) v[j] = src[j];
    } else {
#pragma unroll
      for (int j = 0; j < 8; j++) v[j] = make_float4(0.f, 0.f, 0.f, 0.f);
    }
    unsigned hw[16], lw[16];
#pragma unroll
    for (int j = 0; j < 8; j++) {
      s = fmaf(v[j].x, v[j].x, s); s = fmaf(v[j].y, v[j].y, s);
      s = fmaf(v[j].z, v[j].z, s); s = fmaf(v[j].w, v[j].w, s);
      cvt2(v[j].x, v[j].y, hw[2 * j], lw[2 * j]);
      cvt2(v[j].z, v[j].w, hw[2 * j + 1], lw[2 * j + 1]);
    }
    uint4* dhp = (uint4*)((unsigned char*)(ws + WS_DH) +
                          (((size_t)slice * 16 + kc) * 8 + (row >> 4)) * 1024);
    uint4* dlp = (uint4*)((unsigned char*)(ws + WS_DL) +
                          (((size_t)slice * 16 + kc) * 8 + (row >> 4)) * 1024);
#pragma unroll
    for (int qd = 0; qd < 4; qd++) {
      dhp[qd * 16 + r15] = make_uint4(hw[4 * qd], hw[4 * qd + 1], hw[4 * qd + 2], hw[4 * qd + 3]);
      dlp[qd * 16 + r15] = make_uint4(lw[4 * qd], lw[4 * qd + 1], lw[4 * qd + 2], lw[4 * qd + 3]);
    }
  }
  s += __shfl_xor(s, 1, 64);
  if (h2 == 0) ws[WS_D2 + gr] = (gr < NN) ? s : __builtin_inff();
}

/* ------- K2: GEMM core (NT=128, 256 thr); MODE 0 = sampled full top-10,
   MODE 1 = threshold filter; PRE 1 = register-prefetch pipelined K-loop -- */
struct StageT { unsigned char ah[8192], al[8192], bh[8192], bl[8192]; };
struct EpiT  { float sq[64][132]; };
struct ListT { u64 kl[64][4][KNN]; };

/* MODE 1 only needs the stage buffer (tau is overlaid onto its first
   1024 B after the K-loop, exactly where the old sm.tau member lived)
   -> 32768 B -> exactly 5 blocks/CU of LDS. MODE 0 keeps the epilogue
   buffers (33792 B, 4 blocks/CU). */
template <int MODE> union SmemU { StageT s; EpiT e; ListT l; };
template <> union SmemU<1> { StageT s; };

template <int PRE, int MODE>
__global__ __launch_bounds__(256, 5) void knn_chunk(
    const float* __restrict__ dat, float* __restrict__ ws, int soff) {
  __shared__ __align__(16) SmemU<MODE> sm;
  /* XCD-aware remap (MODE 1): cluster a slice's 8 qblocks onto one XCD,
     adjacent ids (stride 8) so they are co-resident -> B-tile read once
     per XCD instead of 8x from HBM. Bijective for gridDim.y % 8 == 0. */
  int bqx, bsy;
  if (MODE == 1 && (gridDim.y & 7) == 0) {
    const int n = (int)(blockIdx.y * gridDim.x + blockIdx.x);
    const int m = n >> 3;
    const int ypx = (int)(gridDim.y >> 3);
    bqx = m & 7;
    bsy = (n & 7) * ypx + (m >> 3);
  } else {
    bqx = blockIdx.x; bsy = blockIdx.y;
  }
  const int qbase = bqx * QTB;
  const int slice = bsy + soff;
  const int nbase = slice * NT;
  const int t = threadIdx.x;
  const int lane = t & 63, wave = t >> 6;
  const int wn = wave & 1, wq = wave >> 1;
  const unsigned short* xh = (const unsigned short*)(ws + WS_XH);
  const unsigned short* xl = (const unsigned short*)(ws + WS_XL);
  const unsigned char* dh = (const unsigned char*)(ws + WS_DH);
  const unsigned char* dl = (const unsigned char*)(ws + WS_DL);

  f32x4 acc[4][4];
#pragma unroll
  for (int i = 0; i < 4; i++)
#pragma unroll
    for (int j = 0; j < 4; j++) acc[i][j] = (f32x4)0.f;

  if (PRE) {
    /* pipelined: DMA(kc+1) issued after frag reads, overlaps MFMA(kc) */
    auto stage = [&](int kc) {
#pragma unroll
      for (int i = 0; i < 4; i++) {
        int pp = wave * 4 + i;
        int p = pp & 7;
        const unsigned short* g = (pp < 8 ? xh : xl) +
            (size_t)(qbase + p * 16 + (lane & 15)) * DD + kc * 32 + (lane >> 4) * 8;
        glds16(g, (pp < 8 ? sm.s.ah : sm.s.al) + p * 1024);
      }
#pragma unroll
      for (int i = 0; i < 4; i++) {
        int pp = wave * 4 + i;
        int p = pp & 7;
        const unsigned char* g = (pp < 8 ? dh : dl) +
            (((size_t)slice * 16 + kc) * 8 + p) * 1024 + lane * 16;
        glds16(g, (pp < 8 ? sm.s.bh : sm.s.bl) + p * 1024);
      }
    };
    stage(0);
    for (int kc = 0; kc < 16; kc++) {
      __syncthreads();                    /* DMA(kc) complete */
      const int fragoff = lane * 16;
      short8 fah[4], fal[4], fbh[4], fbl[4];
#pragma unroll
      for (int i = 0; i < 4; i++) {
        fah[i] = *(const short8*)(sm.s.ah + (wq * 4 + i) * 1024 + fragoff);
        fal[i] = *(const short8*)(sm.s.al + (wq * 4 + i) * 1024 + fragoff);
        fbh[i] = *(const short8*)(sm.s.bh + (wn * 4 + i) * 1024 + fragoff);
        fbl[i] = *(const short8*)(sm.s.bl + (wn * 4 + i) * 1024 + fragoff);
      }
      __syncthreads();                    /* all waves done reading LDS */
      if (kc < 15) stage(kc + 1);         /* overlaps the MFMAs below */
      /* 3 sweeps of 16: consecutive MFMAs never share an accumulator */
#pragma unroll
      for (int mt = 0; mt < 4; mt++)
#pragma unroll
        for (int nt = 0; nt < 4; nt++)
          acc[mt][nt] = __builtin_amdgcn_mfma_f32_16x16x32_bf16(fah[mt], fbh[nt], acc[mt][nt], 0, 0, 0);
#pragma unroll
      for (int mt = 0; mt < 4; mt++)
#pragma unroll
        for (int nt = 0; nt < 4; nt++)
          acc[mt][nt] = __builtin_amdgcn_mfma_f32_16x16x32_bf16(fah[mt], fbl[nt], acc[mt][nt], 0, 0, 0);
#pragma unroll
      for (int mt = 0; mt < 4; mt++)
#pragma unroll
        for (int nt = 0; nt < 4; nt++)
          acc[mt][nt] = __builtin_amdgcn_mfma_f32_16x16x32_bf16(fal[mt], fbh[nt], acc[mt][nt], 0, 0, 0);
    }
  } else {
    /* fallback: in-loop B conversion (no tiled image in workspace) */
    const int brow = t >> 1, bh_half = t & 1;
    const int bgr = nbase + brow;
    const int bpanel = (brow >> 4) * 1024;
    const int bchunk = (brow & 15) * 16;
    for (int kk = 0; kk < DD; kk += BK) {
      __syncthreads();
#pragma unroll
      for (int i = 0; i < 4; i++) {
        int pp = wave * 4 + i;
        int p = pp & 7;
        const unsigned short* g = (pp < 8 ? xh : xl) +
            (size_t)(qbase + p * 16 + (lane & 15)) * DD + kk + (lane >> 4) * 8;
        glds16(g, (pp < 8 ? sm.s.ah : sm.s.al) + p * 1024);
      }
      {
        float4 v0 = make_float4(0.f, 0.f, 0.f, 0.f), v1 = v0, v2 = v0, v3 = v0;
        if (bgr < NN) {
          const float4* src = (const float4*)(dat + (size_t)bgr * DD + kk + bh_half * 16);
          v0 = src[0]; v1 = src[1]; v2 = src[2]; v3 = src[3];
        }
        unsigned hw[8], lw[8];
        cvt2(v0.x, v0.y, hw[0], lw[0]); cvt2(v0.z, v0.w, hw[1], lw[1]);
        cvt2(v1.x, v1.y, hw[2], lw[2]); cvt2(v1.z, v1.w, hw[3], lw[3]);
        cvt2(v2.x, v2.y, hw[4], lw[4]); cvt2(v2.z, v2.w, hw[5], lw[5]);
        cvt2(v3.x, v3.y, hw[6], lw[6]); cvt2(v3.z, v3.w, hw[7], lw[7]);
        unsigned char* bhp = sm.s.bh + bpanel;
        unsigned char* blp = sm.s.bl + bpanel;
        *(uint4*)(bhp + (2 * bh_half) * 256 + bchunk)     = make_uint4(hw[0], hw[1], hw[2], hw[3]);
        *(uint4*)(bhp + (2 * bh_half + 1) * 256 + bchunk) = make_uint4(hw[4], hw[5], hw[6], hw[7]);
        *(uint4*)(blp + (2 * bh_half) * 256 + bchunk)     = make_uint4(lw[0], lw[1], lw[2], lw[3]);
        *(uint4*)(blp + (2 * bh_half + 1) * 256 + bchunk) = make_uint4(lw[4], lw[5], lw[6], lw[7]);
      }
      __syncthreads();
      const int fragoff = lane * 16;
      short8 fah[4], fal[4], fbh[4], fbl[4];
#pragma unroll
      for (int i = 0; i < 4; i++) {
        fah[i] = *(const short8*)(sm.s.ah + (wq * 4 + i) * 1024 + fragoff);
        fal[i] = *(const short8*)(sm.s.al + (wq * 4 + i) * 1024 + fragoff);
        fbh[i] = *(const short8*)(sm.s.bh + (wn * 4 + i) * 1024 + fragoff);
        fbl[i] = *(const short8*)(sm.s.bl + (wn * 4 + i) * 1024 + fragoff);
      }
#pragma unroll
      for (int mt = 0; mt < 4; mt++)
#pragma unroll
        for (int nt = 0; nt < 4; nt++) {
          acc[mt][nt] = __builtin_amdgcn_mfma_f32_16x16x32_bf16(fah[mt], fbh[nt], acc[mt][nt], 0, 0, 0);
          acc[mt][nt] = __builtin_amdgcn_mfma_f32_16x16x32_bf16(fah[mt], fbl[nt], acc[mt][nt], 0, 0, 0);
          acc[mt][nt] = __builtin_amdgcn_mfma_f32_16x16x32_bf16(fal[mt], fbh[nt], acc[mt][nt], 0, 0, 0);
        }
    }
  }

  if (MODE == 0) {
    SmemU<0>* smp = (SmemU<0>*)&sm;
#pragma unroll
    for (int pass = 0; pass < 2; pass++) {
      __syncthreads();
      if (wq == pass) {
#pragma unroll
        for (int nt = 0; nt < 4; nt++) {
          int col = wn * 64 + nt * 16 + (lane & 15);
          float d2v = ws[WS_D2 + nbase + col];
#pragma unroll
          for (int mt = 0; mt < 4; mt++)
#pragma unroll
            for (int rg = 0; rg < 4; rg++) {
              int lr = mt * 16 + (lane >> 4) * 4 + rg;
              smp->e.sq[lr][col] = fmaf(-2.f, acc[mt][nt][rg], d2v);
            }
        }
      }
      __syncthreads();
      {
        const int r = t >> 2, s = t & 3;
        u64 kl[KNN];
#pragma unroll
        for (int u = 0; u < KNN; u++) kl[u] = ~0ull;
        for (int jj = 0; jj < 32; jj++) {
          int c = s * 32 + ((jj + r + 8 * s) & 31);
          float v = smp->e.sq[r][c];
          ins10(kl, mkkey(v, nbase + c));
        }
        __syncthreads();
#pragma unroll
        for (int u = 0; u < KNN; u++) smp->l.kl[r][s][u] = kl[u];
      }
      __syncthreads();
      if (t < 64) {
        u64* dst = ((u64*)(ws + WS_CKS)) +
                   ((size_t)(qbase + pass * 64 + t) * NSAMP + blockIdx.y) * KNN;
        int h0 = 0, h1 = 0, h2 = 0, h3 = 0;
        for (int pick = 0; pick < KNN; pick++) {
          u64 k0 = smp->l.kl[t][0][h0], k1 = smp->l.kl[t][1][h1];
          u64 k2 = smp->l.kl[t][2][h2], k3 = smp->l.kl[t][3][h3];
          u64 best = k0; int bm = 0;
          if (k1 < best) { best = k1; bm = 1; }
          if (k2 < best) { best = k2; bm = 2; }
          if (k3 < best) { best = k3; bm = 3; }
          dst[pick] = best;
          h0 += (bm == 0); h1 += (bm == 1); h2 += (bm == 2); h3 += (bm == 3);
        }
      }
    }
  } else {
    /* tau overlaid onto the (now dead) stage buffer: frag reads of the
       last K-step completed before its second __syncthreads, so no wave
       still reads sm.s here. */
    __syncthreads();
    u64* taub = (u64*)&sm;
    if (t < 128) taub[t] = ((const u64*)(ws + WS_TAU))[qbase + t];
    __syncthreads();
    unsigned* cnt = (unsigned*)(ws + WS_CNT);
    u64* buf = (u64*)(ws + WS_BUF);
    float d2v[4];
#pragma unroll
    for (int nt = 0; nt < 4; nt++)
      d2v[nt] = ws[WS_D2 + nbase + wn * 64 + nt * 16 + (lane & 15)];
#pragma unroll
    for (int mt = 0; mt < 4; mt++)
#pragma unroll
      for (int rg = 0; rg < 4; rg++) {
        int row = wq * 64 + mt * 16 + (lane >> 4) * 4 + rg;
        u64 tr = taub[row];
#pragma unroll
        for (int nt = 0; nt < 4; nt++) {
          float d = fmaf(-2.f, acc[mt][nt][rg], d2v[nt]);
          int col = nbase + wn * 64 + nt * 16 + (lane & 15);
          u64 key = mkkey(d, col);
          if (key < tr) {
            int q = qbase + row;
            unsigned slot = atomicAdd(cnt + q, 1u);
            if (slot < CAP) buf[(size_t)q * CAP + slot] = key;
          }
        }
      }
  }
}

/* ---------------- K2t: per-query tau = 10th of sampled keys ------------ */
__global__ __launch_bounds__(64) void tau_kernel(float* __restrict__ ws) {
  const int q = blockIdx.x;
  const int t = threadIdx.x;
  const u64* samp = ((const u64*)(ws + WS_CKS)) + (size_t)q * NSAMP * KNN;
  const int NC = NSAMP * KNN;
  u64 kl[KNN];
#pragma unroll
  for (int u = 0; u < KNN; u++) kl[u] = ~0ull;
  for (int j = t; j < NC; j += 64) ins10(kl, samp[j]);
  __shared__ u64 wk[64][KNN];
  __shared__ u64 m2[8][KNN];
#pragma unroll
  for (int u = 0; u < KNN; u++) wk[t][u] = kl[u];
  __syncthreads();
  if (t < 8) {
    int h[8] = {0, 0, 0, 0, 0, 0, 0, 0};
    for (int pick = 0; pick < KNN; pick++) {
      u64 best = ~0ull; int bm = 0;
#pragma unroll
      for (int m = 0; m < 8; m++) {
        u64 km = wk[t * 8 + m][h[m]];
        if (km < best) { best = km; bm = m; }
      }
      m2[t][pick] = best;
#pragma unroll
      for (int m = 0; m < 8; m++) h[m] += (bm == m);
    }
  }
  __syncthreads();
  if (t == 0) {
    int h[8] = {0, 0, 0, 0, 0, 0, 0, 0};
    u64 best = 0;
    for (int pick = 0; pick < KNN; pick++) {
      best = ~0ull; int bm = 0;
#pragma unroll
      for (int m = 0; m < 8; m++) {
        u64 km = m2[m][h[m]];
        if (km < best) { best = km; bm = m; }
      }
#pragma unroll
      for (int m = 0; m < 8; m++) h[m] += (bm == m);
    }
    ((u64*)(ws + WS_TAU))[q] = best;
    ((unsigned*)(ws + WS_CNT))[q] = 0u;
  }
}

/* ---------------- K3: final top-10 (sampled + survivors) + mode -------- */
__global__ __launch_bounds__(64) void knn_final(
    const int* __restrict__ targets, float* __restrict__ ws,
    float* __restrict__ out) {
  const int q = blockIdx.x;
  const int t = threadIdx.x;
  const u64* samp = ((const u64*)(ws + WS_CKS)) + (size_t)q * NSAMP * KNN;
  const u64* buf = ((const u64*)(ws + WS_BUF)) + (size_t)q * CAP;
  unsigned c = ((const unsigned*)(ws + WS_CNT))[q];
  if (c > CAP) c = CAP;

  u64 kl[KNN];
#pragma unroll
  for (int u = 0; u < KNN; u++) kl[u] = ~0ull;
  for (int j = t; j < NSAMP * KNN; j += 64) ins10(kl, samp[j]);
  for (int j = t; j < (int)c; j += 64) ins10(kl, buf[j]);

  __shared__ u64 wk[64][KNN];
  __shared__ u64 m2[8][KNN];
#pragma unroll
  for (int u = 0; u < KNN; u++) wk[t][u] = kl[u];
  __syncthreads();
  if (t < 8) {
    int h[8] = {0, 0, 0, 0, 0, 0, 0, 0};
    for (int pick = 0; pick < KNN; pick++) {
      u64 best = ~0ull; int bm = 0;
#pragma unroll
      for (int m = 0; m < 8; m++) {
        u64 km = wk[t * 8 + m][h[m]];
        if (km < best) { best = km; bm = m; }
      }
      m2[t][pick] = best;
#pragma unroll
      for (int m = 0; m < 8; m++) h[m] += (bm == m);
    }
  }
  __syncthreads();
  if (t == 0) {
    int h[8] = {0, 0, 0, 0, 0, 0, 0, 0};
    int fi[KNN];
    for (int pick = 0; pick < KNN; pick++) {
      u64 best = ~0ull; int bm = 0;
#pragma unroll
      for (int m = 0; m < 8; m++) {
        u64 km = m2[m][h[m]];
        if (km < best) { best = km; bm = m; }
      }
      fi[pick] = (int)(unsigned)(best & 0xffffffffu);
#pragma unroll
      for (int m = 0; m < 8; m++) h[m] += (bm == m);
    }
    int lab[KNN];
#pragma unroll
    for (int u = 0; u < KNN; u++) lab[u] = targets[fi[u]];
    int bc = 0, bl = INT_MAX;
#pragma unroll
    for (int i = 0; i < KNN; i++) {
      int cc = 0;
#pragma unroll
      for (int j = 0; j < KNN; j++) cc += (lab[j] == lab[i]) ? 1 : 0;
      if (cc > bc || (cc == bc && lab[i] < bl)) { bc = cc; bl = lab[i]; }
    }
    out[q] = (float)bl;
  }
}

extern "C" void kernel_launch(void* const* d_in, const int* in_sizes, int n_in,
                              void* d_out, int out_size, void* d_ws, size_t ws_size,
                              hipStream_t stream) {
  const float* Xm  = (const float*)d_in[0];
  const float* dat = (const float*)d_in[1];
  const int* targets = (const int*)d_in[2];
  float* out = (float*)d_out;
  float* ws  = (float*)d_ws;
  const bool pre = ws_size >= (size_t)WS_END * 4;   /* constant per process */

  hipLaunchKernelGGL(convx_kernel, dim3(QN / 4), dim3(256), 0, stream, Xm, ws);
  hipLaunchKernelGGL(convd_kernel, dim3(NS), dim3(256), 0, stream, dat, ws);
  if (pre) {
    hipLaunchKernelGGL((knn_chunk<1, 0>), dim3(QB, NSAMP), dim3(256), 0, stream, dat, ws, 0);
    hipLaunchKernelGGL(tau_kernel, dim3(QN), dim3(64), 0, stream, ws);
    hipLaunchKernelGGL((knn_chunk<1, 1>), dim3(QB, NREST), dim3(256), 0, stream, dat, ws, NSAMP);
  } else {
    hipLaunchKernelGGL((knn_chunk<0, 0>), dim3(QB, NSAMP), dim3(256), 0, stream, dat, ws, 0);
    hipLaunchKernelGGL(tau_kernel, dim3(QN), dim3(64), 0, stream, ws);
    hipLaunchKernelGGL((knn_chunk<0, 1>), dim3(QB, NREST), dim3(256), 0, stream, dat, ws, NSAMP);
  }
  hipLaunchKernelGGL(knn_final, dim3(QN), dim3(64), 0, stream, targets, ws, out);
}

// Round 3
// 376.379 us; speedup vs baseline: 1.9535x; 1.9535x over previous
//
#include <hip/hip_runtime.h>
#include <math.h>
#include <limits.h>

#define QN 1024
#define NN 50000
#define NPAD 50048        /* 391*128 exactly */
#define DD 512
#define KNN 10
#define NT 128
#define QTB 128
#define BK 32
#define NS 391
#define QB 8
#define NSAMP 31
#define NREST (NS - NSAMP)    /* 360 */
#define CAP 512

/* workspace layout, in 4-byte words */
#define WS_D2  0
#define WS_TAU 50048                       /* u64[1024] */
#define WS_CNT (WS_TAU + 2048)
#define WS_XH  (WS_CNT + 1024)
#define WS_XL  (WS_XH + QN * DD / 2)
#define WS_CKS (WS_XL + QN * DD / 2)       /* u64[QN*NSAMP*KNN] */
#define WS_BUF (WS_CKS + QN * NSAMP * KNN * 2)
#define WS_DH  (WS_BUF + QN * CAP * 2)     /* tiled data hi: 391*16*8192 B */
#define WS_DL  (WS_DH + NS * 16 * 2048)
#define WS_END (WS_DL + NS * 16 * 2048)

typedef __attribute__((ext_vector_type(8))) short short8;
typedef __attribute__((ext_vector_type(4))) float f32x4;
typedef unsigned long long u64;

__device__ __forceinline__ u64 mkkey(float f, int idx) {
  unsigned u = __float_as_uint(f);
  unsigned m = u ^ ((unsigned)((int)u >> 31) | 0x80000000u);
  return ((u64)m << 32) | (unsigned)idx;
}

__device__ __forceinline__ void cvt2(float x, float y, unsigned& hi, unsigned& lo) {
  unsigned ux = __float_as_uint(x), uy = __float_as_uint(y);
  unsigned rx = ux + 0x7fffu + ((ux >> 16) & 1u);
  unsigned ry = uy + 0x7fffu + ((uy >> 16) & 1u);
  hi = (rx >> 16) | (ry & 0xffff0000u);
  float xl = x - __uint_as_float(rx & 0xffff0000u);
  float yl = y - __uint_as_float(ry & 0xffff0000u);
  unsigned uxl = __float_as_uint(xl), uyl = __float_as_uint(yl);
  unsigned rxl = uxl + 0x7fffu + ((uxl >> 16) & 1u);
  unsigned ryl = uyl + 0x7fffu + ((uyl >> 16) & 1u);
  lo = (rxl >> 16) | (ryl & 0xffff0000u);
}

__device__ __forceinline__ void glds16(const void* g, void* l) {
  __builtin_amdgcn_global_load_lds(
      (const __attribute__((address_space(1))) unsigned*)g,
      (__attribute__((address_space(3))) unsigned*)l, 16, 0, 0);
}

__device__ __forceinline__ void ins10(u64* kl, u64 k) {
#pragma unroll
  for (int u = 0; u < KNN; u++) {
    u64 lo = (k < kl[u]) ? k : kl[u];
    u64 hi = (k < kl[u]) ? kl[u] : k;
    kl[u] = lo; k = hi;
  }
}

/* ---------------- K0: preconvert X to split-bf16 row-major -------------- */
__global__ __launch_bounds__(256) void convx_kernel(
    const float* __restrict__ Xm, float* __restrict__ ws) {
  int w = threadIdx.x >> 6, lane = threadIdx.x & 63;
  int row = blockIdx.x * 4 + w;
  const float4* p = (const float4*)(Xm + (size_t)row * DD) + lane * 2;
  float4 v0 = p[0], v1 = p[1];
  unsigned h[4], l[4];
  cvt2(v0.x, v0.y, h[0], l[0]); cvt2(v0.z, v0.w, h[1], l[1]);
  cvt2(v1.x, v1.y, h[2], l[2]); cvt2(v1.z, v1.w, h[3], l[3]);
  ((uint4*)(ws + WS_XH))[row * 64 + lane] = make_uint4(h[0], h[1], h[2], h[3]);
  ((uint4*)(ws + WS_XL))[row * 64 + lane] = make_uint4(l[0], l[1], l[2], l[3]);
}

/* ------- K1: fused data preconvert (tiled split-bf16) + row norms -------
   (r0-proven version) ----------------------------------------------------- */
__global__ __launch_bounds__(256) void convd_kernel(
    const float* __restrict__ dat, float* __restrict__ ws) {
  const int slice = blockIdx.x;
  const int t = threadIdx.x;
  const int row = t >> 1, h2 = t & 1;
  const int gr = slice * NT + row;
  const int r15 = row & 15;
  float s = 0.f;
#pragma unroll
  for (int kc8 = 0; kc8 < 8; kc8++) {
    const int kc = h2 * 8 + kc8;
    float4 v[8];
    if (gr < NN) {
      const float4* src = (const float4*)(dat + (size_t)gr * DD + kc * 32);
#pragma unroll
      for (int j = 0; j < 8; j++) v[j] = src[j];
    } else {
#pragma unroll
      for (int j = 0; j < 8; j++) v[j] = make_float4(0.f, 0.f, 0.f, 0.f);
    }
    unsigned hw[16], lw[16];
#pragma unroll
    for (int j = 0; j < 8; j++) {
      s = fmaf(v[j].x, v[j].x, s); s = fmaf(v[j].y, v[j].y, s);
      s = fmaf(v[j].z, v[j].z, s); s = fmaf(v[j].w, v[j].w, s);
      cvt2(v[j].x, v[j].y, hw[2 * j], lw[2 * j]);
      cvt2(v[j].z, v[j].w, hw[2 * j + 1], lw[2 * j + 1]);
    }
    uint4* dhp = (uint4*)((unsigned char*)(ws + WS_DH) +
                          (((size_t)slice * 16 + kc) * 8 + (row >> 4)) * 1024);
    uint4* dlp = (uint4*)((unsigned char*)(ws + WS_DL) +
                          (((size_t)slice * 16 + kc) * 8 + (row >> 4)) * 1024);
#pragma unroll
    for (int qd = 0; qd < 4; qd++) {
      dhp[qd * 16 + r15] = make_uint4(hw[4 * qd], hw[4 * qd + 1], hw[4 * qd + 2], hw[4 * qd + 3]);
      dlp[qd * 16 + r15] = make_uint4(lw[4 * qd], lw[4 * qd + 1], lw[4 * qd + 2], lw[4 * qd + 3]);
    }
  }
  s += __shfl_xor(s, 1, 64);
  if (h2 == 0) ws[WS_D2 + gr] = (gr < NN) ? s : __builtin_inff();
}

/* ------- K2: GEMM core (NT=128, 256 thr); MODE 0 = sampled full top-10,
   MODE 1 = threshold filter; PRE 1 = register-prefetch pipelined K-loop -- */
struct StageT { unsigned char ah[8192], al[8192], bh[8192], bl[8192]; };
struct EpiT  { float sq[64][132]; };
struct ListT { u64 kl[64][4][KNN]; };

/* MODE 1 only needs the stage buffer (tau overlaid after the K-loop).
   NOTE r2 lesson: do NOT pair this with __launch_bounds__ min-waves=5 —
   the 102-VGPR cap spills the 64-AGPR accumulator (VGPR 64->48, 1.15 GB
   scratch writes, 387->735 us). Occupancy is register-limited at 4
   blocks/CU regardless; keep (256,3). */
template <int MODE> union SmemU { StageT s; EpiT e; ListT l; };
template <> union SmemU<1> { StageT s; };

template <int PRE, int MODE>
__global__ __launch_bounds__(256, 3) void knn_chunk(
    const float* __restrict__ dat, float* __restrict__ ws, int soff) {
  __shared__ __align__(16) SmemU<MODE> sm;
  /* XCD-aware remap (MODE 1): cluster a slice's 8 qblocks onto one XCD,
     adjacent ids (stride 8) so they are co-resident -> B-tile read once
     per XCD instead of 8x from HBM. Bijective for gridDim.y % 8 == 0. */
  int bqx, bsy;
  if (MODE == 1 && (gridDim.y & 7) == 0) {
    const int n = (int)(blockIdx.y * gridDim.x + blockIdx.x);
    const int m = n >> 3;
    const int ypx = (int)(gridDim.y >> 3);
    bqx = m & 7;
    bsy = (n & 7) * ypx + (m >> 3);
  } else {
    bqx = blockIdx.x; bsy = blockIdx.y;
  }
  const int qbase = bqx * QTB;
  const int slice = bsy + soff;
  const int nbase = slice * NT;
  const int t = threadIdx.x;
  const int lane = t & 63, wave = t >> 6;
  const int wn = wave & 1, wq = wave >> 1;
  const unsigned short* xh = (const unsigned short*)(ws + WS_XH);
  const unsigned short* xl = (const unsigned short*)(ws + WS_XL);
  const unsigned char* dh = (const unsigned char*)(ws + WS_DH);
  const unsigned char* dl = (const unsigned char*)(ws + WS_DL);

  f32x4 acc[4][4];
#pragma unroll
  for (int i = 0; i < 4; i++)
#pragma unroll
    for (int j = 0; j < 4; j++) acc[i][j] = (f32x4)0.f;

  if (PRE) {
    /* pipelined: DMA(kc+1) issued after frag reads, overlaps MFMA(kc) */
    auto stage = [&](int kc) {
#pragma unroll
      for (int i = 0; i < 4; i++) {
        int pp = wave * 4 + i;
        int p = pp & 7;
        const unsigned short* g = (pp < 8 ? xh : xl) +
            (size_t)(qbase + p * 16 + (lane & 15)) * DD + kc * 32 + (lane >> 4) * 8;
        glds16(g, (pp < 8 ? sm.s.ah : sm.s.al) + p * 1024);
      }
#pragma unroll
      for (int i = 0; i < 4; i++) {
        int pp = wave * 4 + i;
        int p = pp & 7;
        const unsigned char* g = (pp < 8 ? dh : dl) +
            (((size_t)slice * 16 + kc) * 8 + p) * 1024 + lane * 16;
        glds16(g, (pp < 8 ? sm.s.bh : sm.s.bl) + p * 1024);
      }
    };
    stage(0);
    for (int kc = 0; kc < 16; kc++) {
      __syncthreads();                    /* DMA(kc) complete */
      const int fragoff = lane * 16;
      short8 fah[4], fal[4], fbh[4], fbl[4];
#pragma unroll
      for (int i = 0; i < 4; i++) {
        fah[i] = *(const short8*)(sm.s.ah + (wq * 4 + i) * 1024 + fragoff);
        fal[i] = *(const short8*)(sm.s.al + (wq * 4 + i) * 1024 + fragoff);
        fbh[i] = *(const short8*)(sm.s.bh + (wn * 4 + i) * 1024 + fragoff);
        fbl[i] = *(const short8*)(sm.s.bl + (wn * 4 + i) * 1024 + fragoff);
      }
      __syncthreads();                    /* all waves done reading LDS */
      if (kc < 15) stage(kc + 1);         /* overlaps the MFMAs below */
      /* 3 sweeps of 16: consecutive MFMAs never share an accumulator */
#pragma unroll
      for (int mt = 0; mt < 4; mt++)
#pragma unroll
        for (int nt = 0; nt < 4; nt++)
          acc[mt][nt] = __builtin_amdgcn_mfma_f32_16x16x32_bf16(fah[mt], fbh[nt], acc[mt][nt], 0, 0, 0);
#pragma unroll
      for (int mt = 0; mt < 4; mt++)
#pragma unroll
        for (int nt = 0; nt < 4; nt++)
          acc[mt][nt] = __builtin_amdgcn_mfma_f32_16x16x32_bf16(fah[mt], fbl[nt], acc[mt][nt], 0, 0, 0);
#pragma unroll
      for (int mt = 0; mt < 4; mt++)
#pragma unroll
        for (int nt = 0; nt < 4; nt++)
          acc[mt][nt] = __builtin_amdgcn_mfma_f32_16x16x32_bf16(fal[mt], fbh[nt], acc[mt][nt], 0, 0, 0);
    }
  } else {
    /* fallback: in-loop B conversion (no tiled image in workspace) */
    const int brow = t >> 1, bh_half = t & 1;
    const int bgr = nbase + brow;
    const int bpanel = (brow >> 4) * 1024;
    const int bchunk = (brow & 15) * 16;
    for (int kk = 0; kk < DD; kk += BK) {
      __syncthreads();
#pragma unroll
      for (int i = 0; i < 4; i++) {
        int pp = wave * 4 + i;
        int p = pp & 7;
        const unsigned short* g = (pp < 8 ? xh : xl) +
            (size_t)(qbase + p * 16 + (lane & 15)) * DD + kk + (lane >> 4) * 8;
        glds16(g, (pp < 8 ? sm.s.ah : sm.s.al) + p * 1024);
      }
      {
        float4 v0 = make_float4(0.f, 0.f, 0.f, 0.f), v1 = v0, v2 = v0, v3 = v0;
        if (bgr < NN) {
          const float4* src = (const float4*)(dat + (size_t)bgr * DD + kk + bh_half * 16);
          v0 = src[0]; v1 = src[1]; v2 = src[2]; v3 = src[3];
        }
        unsigned hw[8], lw[8];
        cvt2(v0.x, v0.y, hw[0], lw[0]); cvt2(v0.z, v0.w, hw[1], lw[1]);
        cvt2(v1.x, v1.y, hw[2], lw[2]); cvt2(v1.z, v1.w, hw[3], lw[3]);
        cvt2(v2.x, v2.y, hw[4], lw[4]); cvt2(v2.z, v2.w, hw[5], lw[5]);
        cvt2(v3.x, v3.y, hw[6], lw[6]); cvt2(v3.z, v3.w, hw[7], lw[7]);
        unsigned char* bhp = sm.s.bh + bpanel;
        unsigned char* blp = sm.s.bl + bpanel;
        *(uint4*)(bhp + (2 * bh_half) * 256 + bchunk)     = make_uint4(hw[0], hw[1], hw[2], hw[3]);
        *(uint4*)(bhp + (2 * bh_half + 1) * 256 + bchunk) = make_uint4(hw[4], hw[5], hw[6], hw[7]);
        *(uint4*)(blp + (2 * bh_half) * 256 + bchunk)     = make_uint4(lw[0], lw[1], lw[2], lw[3]);
        *(uint4*)(blp + (2 * bh_half + 1) * 256 + bchunk) = make_uint4(lw[4], lw[5], lw[6], lw[7]);
      }
      __syncthreads();
      const int fragoff = lane * 16;
      short8 fah[4], fal[4], fbh[4], fbl[4];
#pragma unroll
      for (int i = 0; i < 4; i++) {
        fah[i] = *(const short8*)(sm.s.ah + (wq * 4 + i) * 1024 + fragoff);
        fal[i] = *(const short8*)(sm.s.al + (wq * 4 + i) * 1024 + fragoff);
        fbh[i] = *(const short8*)(sm.s.bh + (wn * 4 + i) * 1024 + fragoff);
        fbl[i] = *(const short8*)(sm.s.bl + (wn * 4 + i) * 1024 + fragoff);
      }
#pragma unroll
      for (int mt = 0; mt < 4; mt++)
#pragma unroll
        for (int nt = 0; nt < 4; nt++) {
          acc[mt][nt] = __builtin_amdgcn_mfma_f32_16x16x32_bf16(fah[mt], fbh[nt], acc[mt][nt], 0, 0, 0);
          acc[mt][nt] = __builtin_amdgcn_mfma_f32_16x16x32_bf16(fah[mt], fbl[nt], acc[mt][nt], 0, 0, 0);
          acc[mt][nt] = __builtin_amdgcn_mfma_f32_16x16x32_bf16(fal[mt], fbh[nt], acc[mt][nt], 0, 0, 0);
        }
    }
  }

  if (MODE == 0) {
    SmemU<0>* smp = (SmemU<0>*)&sm;
#pragma unroll
    for (int pass = 0; pass < 2; pass++) {
      __syncthreads();
      if (wq == pass) {
#pragma unroll
        for (int nt = 0; nt < 4; nt++) {
          int col = wn * 64 + nt * 16 + (lane & 15);
          float d2v = ws[WS_D2 + nbase + col];
#pragma unroll
          for (int mt = 0; mt < 4; mt++)
#pragma unroll
            for (int rg = 0; rg < 4; rg++) {
              int lr = mt * 16 + (lane >> 4) * 4 + rg;
              smp->e.sq[lr][col] = fmaf(-2.f, acc[mt][nt][rg], d2v);
            }
        }
      }
      __syncthreads();
      {
        const int r = t >> 2, s = t & 3;
        u64 kl[KNN];
#pragma unroll
        for (int u = 0; u < KNN; u++) kl[u] = ~0ull;
        for (int jj = 0; jj < 32; jj++) {
          int c = s * 32 + ((jj + r + 8 * s) & 31);
          float v = smp->e.sq[r][c];
          ins10(kl, mkkey(v, nbase + c));
        }
        __syncthreads();
#pragma unroll
        for (int u = 0; u < KNN; u++) smp->l.kl[r][s][u] = kl[u];
      }
      __syncthreads();
      if (t < 64) {
        u64* dst = ((u64*)(ws + WS_CKS)) +
                   ((size_t)(qbase + pass * 64 + t) * NSAMP + blockIdx.y) * KNN;
        int h0 = 0, h1 = 0, h2 = 0, h3 = 0;
        for (int pick = 0; pick < KNN; pick++) {
          u64 k0 = smp->l.kl[t][0][h0], k1 = smp->l.kl[t][1][h1];
          u64 k2 = smp->l.kl[t][2][h2], k3 = smp->l.kl[t][3][h3];
          u64 best = k0; int bm = 0;
          if (k1 < best) { best = k1; bm = 1; }
          if (k2 < best) { best = k2; bm = 2; }
          if (k3 < best) { best = k3; bm = 3; }
          dst[pick] = best;
          h0 += (bm == 0); h1 += (bm == 1); h2 += (bm == 2); h3 += (bm == 3);
        }
      }
    }
  } else {
    /* tau overlaid onto the (now dead) stage buffer: frag reads of the
       last K-step completed before its second __syncthreads, so no wave
       still reads sm.s here. */
    __syncthreads();
    u64* taub = (u64*)&sm;
    if (t < 128) taub[t] = ((const u64*)(ws + WS_TAU))[qbase + t];
    __syncthreads();
    unsigned* cnt = (unsigned*)(ws + WS_CNT);
    u64* buf = (u64*)(ws + WS_BUF);
    float d2v[4];
#pragma unroll
    for (int nt = 0; nt < 4; nt++)
      d2v[nt] = ws[WS_D2 + nbase + wn * 64 + nt * 16 + (lane & 15)];
#pragma unroll
    for (int mt = 0; mt < 4; mt++)
#pragma unroll
      for (int rg = 0; rg < 4; rg++) {
        int row = wq * 64 + mt * 16 + (lane >> 4) * 4 + rg;
        u64 tr = taub[row];
#pragma unroll
        for (int nt = 0; nt < 4; nt++) {
          float d = fmaf(-2.f, acc[mt][nt][rg], d2v[nt]);
          int col = nbase + wn * 64 + nt * 16 + (lane & 15);
          u64 key = mkkey(d, col);
          if (key < tr) {
            int q = qbase + row;
            unsigned slot = atomicAdd(cnt + q, 1u);
            if (slot < CAP) buf[(size_t)q * CAP + slot] = key;
          }
        }
      }
  }
}

/* ---------------- K2t: per-query tau = 10th of sampled keys ------------ */
__global__ __launch_bounds__(64) void tau_kernel(float* __restrict__ ws) {
  const int q = blockIdx.x;
  const int t = threadIdx.x;
  const u64* samp = ((const u64*)(ws + WS_CKS)) + (size_t)q * NSAMP * KNN;
  const int NC = NSAMP * KNN;
  u64 kl[KNN];
#pragma unroll
  for (int u = 0; u < KNN; u++) kl[u] = ~0ull;
  for (int j = t; j < NC; j += 64) ins10(kl, samp[j]);
  __shared__ u64 wk[64][KNN];
  __shared__ u64 m2[8][KNN];
#pragma unroll
  for (int u = 0; u < KNN; u++) wk[t][u] = kl[u];
  __syncthreads();
  if (t < 8) {
    int h[8] = {0, 0, 0, 0, 0, 0, 0, 0};
    for (int pick = 0; pick < KNN; pick++) {
      u64 best = ~0ull; int bm = 0;
#pragma unroll
      for (int m = 0; m < 8; m++) {
        u64 km = wk[t * 8 + m][h[m]];
        if (km < best) { best = km; bm = m; }
      }
      m2[t][pick] = best;
#pragma unroll
      for (int m = 0; m < 8; m++) h[m] += (bm == m);
    }
  }
  __syncthreads();
  if (t == 0) {
    int h[8] = {0, 0, 0, 0, 0, 0, 0, 0};
    u64 best = 0;
    for (int pick = 0; pick < KNN; pick++) {
      best = ~0ull; int bm = 0;
#pragma unroll
      for (int m = 0; m < 8; m++) {
        u64 km = m2[m][h[m]];
        if (km < best) { best = km; bm = m; }
      }
#pragma unroll
      for (int m = 0; m < 8; m++) h[m] += (bm == m);
    }
    ((u64*)(ws + WS_TAU))[q] = best;
    ((unsigned*)(ws + WS_CNT))[q] = 0u;
  }
}

/* ---------------- K3: final top-10 (sampled + survivors) + mode -------- */
__global__ __launch_bounds__(64) void knn_final(
    const int* __restrict__ targets, float* __restrict__ ws,
    float* __restrict__ out) {
  const int q = blockIdx.x;
  const int t = threadIdx.x;
  const u64* samp = ((const u64*)(ws + WS_CKS)) + (size_t)q * NSAMP * KNN;
  const u64* buf = ((const u64*)(ws + WS_BUF)) + (size_t)q * CAP;
  unsigned c = ((const unsigned*)(ws + WS_CNT))[q];
  if (c > CAP) c = CAP;

  u64 kl[KNN];
#pragma unroll
  for (int u = 0; u < KNN; u++) kl[u] = ~0ull;
  for (int j = t; j < NSAMP * KNN; j += 64) ins10(kl, samp[j]);
  for (int j = t; j < (int)c; j += 64) ins10(kl, buf[j]);

  __shared__ u64 wk[64][KNN];
  __shared__ u64 m2[8][KNN];
#pragma unroll
  for (int u = 0; u < KNN; u++) wk[t][u] = kl[u];
  __syncthreads();
  if (t < 8) {
    int h[8] = {0, 0, 0, 0, 0, 0, 0, 0};
    for (int pick = 0; pick < KNN; pick++) {
      u64 best = ~0ull; int bm = 0;
#pragma unroll
      for (int m = 0; m < 8; m++) {
        u64 km = wk[t * 8 + m][h[m]];
        if (km < best) { best = km; bm = m; }
      }
      m2[t][pick] = best;
#pragma unroll
      for (int m = 0; m < 8; m++) h[m] += (bm == m);
    }
  }
  __syncthreads();
  if (t == 0) {
    int h[8] = {0, 0, 0, 0, 0, 0, 0, 0};
    int fi[KNN];
    for (int pick = 0; pick < KNN; pick++) {
      u64 best = ~0ull; int bm = 0;
#pragma unroll
      for (int m = 0; m < 8; m++) {
        u64 km = m2[m][h[m]];
        if (km < best) { best = km; bm = m; }
      }
      fi[pick] = (int)(unsigned)(best & 0xffffffffu);
#pragma unroll
      for (int m = 0; m < 8; m++) h[m] += (bm == m);
    }
    int lab[KNN];
#pragma unroll
    for (int u = 0; u < KNN; u++) lab[u] = targets[fi[u]];
    int bc = 0, bl = INT_MAX;
#pragma unroll
    for (int i = 0; i < KNN; i++) {
      int cc = 0;
#pragma unroll
      for (int j = 0; j < KNN; j++) cc += (lab[j] == lab[i]) ? 1 : 0;
      if (cc > bc || (cc == bc && lab[i] < bl)) { bc = cc; bl = lab[i]; }
    }
    out[q] = (float)bl;
  }
}

extern "C" void kernel_launch(void* const* d_in, const int* in_sizes, int n_in,
                              void* d_out, int out_size, void* d_ws, size_t ws_size,
                              hipStream_t stream) {
  const float* Xm  = (const float*)d_in[0];
  const float* dat = (const float*)d_in[1];
  const int* targets = (const int*)d_in[2];
  float* out = (float*)d_out;
  float* ws  = (float*)d_ws;
  const bool pre = ws_size >= (size_t)WS_END * 4;   /* constant per process */

  hipLaunchKernelGGL(convx_kernel, dim3(QN / 4), dim3(256), 0, stream, Xm, ws);
  hipLaunchKernelGGL(convd_kernel, dim3(NS), dim3(256), 0, stream, dat, ws);
  if (pre) {
    hipLaunchKernelGGL((knn_chunk<1, 0>), dim3(QB, NSAMP), dim3(256), 0, stream, dat, ws, 0);
    hipLaunchKernelGGL(tau_kernel, dim3(QN), dim3(64), 0, stream, ws);
    hipLaunchKernelGGL((knn_chunk<1, 1>), dim3(QB, NREST), dim3(256), 0, stream, dat, ws, NSAMP);
  } else {
    hipLaunchKernelGGL((knn_chunk<0, 0>), dim3(QB, NSAMP), dim3(256), 0, stream, dat, ws, 0);
    hipLaunchKernelGGL(tau_kernel, dim3(QN), dim3(64), 0, stream, ws);
    hipLaunchKernelGGL((knn_chunk<0, 1>), dim3(QB, NREST), dim3(256), 0, stream, dat, ws, NSAMP);
  }
  hipLaunchKernelGGL(knn_final, dim3(QN), dim3(64), 0, stream, targets, ws, out);
}

// Round 4
// 363.900 us; speedup vs baseline: 2.0205x; 1.0343x over previous
//
#include <hip/hip_runtime.h>
#include <math.h>
#include <limits.h>

#define QN 1024
#define NN 50000
#define NPAD 50048        /* 391*128 exactly */
#define DD 512
#define KNN 10
#define NT 128
#define QTB 128
#define BK 32
#define NS 391
#define QB 8
#define NSAMP 31
#define NREST (NS - NSAMP)    /* 360 */
#define CAP 512

/* workspace layout, in 4-byte words */
#define WS_D2  0
#define WS_TAU 50048                       /* u64[1024] */
#define WS_CNT (WS_TAU + 2048)
#define WS_XH  (WS_CNT + 1024)
#define WS_XL  (WS_XH + QN * DD / 2)
#define WS_CKS (WS_XL + QN * DD / 2)       /* u64[QN*NSAMP*KNN] */
#define WS_BUF (WS_CKS + QN * NSAMP * KNN * 2)
#define WS_DH  (WS_BUF + QN * CAP * 2)     /* tiled data hi: 391*16*8192 B */
#define WS_DL  (WS_DH + NS * 16 * 2048)
#define WS_END (WS_DL + NS * 16 * 2048)

typedef __attribute__((ext_vector_type(8))) short short8;
typedef __attribute__((ext_vector_type(4))) float f32x4;
typedef unsigned long long u64;

__device__ __forceinline__ u64 mkkey(float f, int idx) {
  unsigned u = __float_as_uint(f);
  unsigned m = u ^ ((unsigned)((int)u >> 31) | 0x80000000u);
  return ((u64)m << 32) | (unsigned)idx;
}

__device__ __forceinline__ void cvt2(float x, float y, unsigned& hi, unsigned& lo) {
  unsigned ux = __float_as_uint(x), uy = __float_as_uint(y);
  unsigned rx = ux + 0x7fffu + ((ux >> 16) & 1u);
  unsigned ry = uy + 0x7fffu + ((uy >> 16) & 1u);
  hi = (rx >> 16) | (ry & 0xffff0000u);
  float xl = x - __uint_as_float(rx & 0xffff0000u);
  float yl = y - __uint_as_float(ry & 0xffff0000u);
  unsigned uxl = __float_as_uint(xl), uyl = __float_as_uint(yl);
  unsigned rxl = uxl + 0x7fffu + ((uxl >> 16) & 1u);
  unsigned ryl = uyl + 0x7fffu + ((uyl >> 16) & 1u);
  lo = (rxl >> 16) | (ryl & 0xffff0000u);
}

__device__ __forceinline__ void glds16(const void* g, void* l) {
  __builtin_amdgcn_global_load_lds(
      (const __attribute__((address_space(1))) unsigned*)g,
      (__attribute__((address_space(3))) unsigned*)l, 16, 0, 0);
}

__device__ __forceinline__ void ins10(u64* kl, u64 k) {
#pragma unroll
  for (int u = 0; u < KNN; u++) {
    u64 lo = (k < kl[u]) ? k : kl[u];
    u64 hi = (k < kl[u]) ? kl[u] : k;
    kl[u] = lo; k = hi;
  }
}

/* ---------------- K0: preconvert X to frag-direct split-bf16 ------------
   New layout (A out of LDS): 16B block index g = (b*16 + kc)*64 + l where
   b = row>>4 (0..63), kc = col-chunk-of-32 (0..15), l = sub*16 + (row&15),
   sub = (col>>3)&3. Lane l of a GEMM wave reads block ((b*16+kc)*64+l)
   directly -> one coalesced global_load_dwordx4 per A-fragment, byte-
   identical to what the old LDS staging delivered. ---------------------- */
__global__ __launch_bounds__(256) void convx_kernel(
    const float* __restrict__ Xm, float* __restrict__ ws) {
  const int g = blockIdx.x * 256 + threadIdx.x;   /* 0..65535 */
  const int b = g >> 10, kc = (g >> 6) & 15, l = g & 63;
  const int row = b * 16 + (l & 15);
  const int col = kc * 32 + (l >> 4) * 8;
  const float4* p = (const float4*)(Xm + (size_t)row * DD + col);
  float4 v0 = p[0], v1 = p[1];
  unsigned h[4], lo[4];
  cvt2(v0.x, v0.y, h[0], lo[0]); cvt2(v0.z, v0.w, h[1], lo[1]);
  cvt2(v1.x, v1.y, h[2], lo[2]); cvt2(v1.z, v1.w, h[3], lo[3]);
  ((uint4*)(ws + WS_XH))[g] = make_uint4(h[0], h[1], h[2], h[3]);
  ((uint4*)(ws + WS_XL))[g] = make_uint4(lo[0], lo[1], lo[2], lo[3]);
}

/* ------- K1: fused data preconvert (tiled split-bf16) + row norms -------
   (r0-proven version, unchanged) ----------------------------------------- */
__global__ __launch_bounds__(256) void convd_kernel(
    const float* __restrict__ dat, float* __restrict__ ws) {
  const int slice = blockIdx.x;
  const int t = threadIdx.x;
  const int row = t >> 1, h2 = t & 1;
  const int gr = slice * NT + row;
  const int r15 = row & 15;
  float s = 0.f;
#pragma unroll
  for (int kc8 = 0; kc8 < 8; kc8++) {
    const int kc = h2 * 8 + kc8;
    float4 v[8];
    if (gr < NN) {
      const float4* src = (const float4*)(dat + (size_t)gr * DD + kc * 32);
#pragma unroll
      for (int j = 0; j < 8; j++) v[j] = src[j];
    } else {
#pragma unroll
      for (int j = 0; j < 8; j++) v[j] = make_float4(0.f, 0.f, 0.f, 0.f);
    }
    unsigned hw[16], lw[16];
#pragma unroll
    for (int j = 0; j < 8; j++) {
      s = fmaf(v[j].x, v[j].x, s); s = fmaf(v[j].y, v[j].y, s);
      s = fmaf(v[j].z, v[j].z, s); s = fmaf(v[j].w, v[j].w, s);
      cvt2(v[j].x, v[j].y, hw[2 * j], lw[2 * j]);
      cvt2(v[j].z, v[j].w, hw[2 * j + 1], lw[2 * j + 1]);
    }
    uint4* dhp = (uint4*)((unsigned char*)(ws + WS_DH) +
                          (((size_t)slice * 16 + kc) * 8 + (row >> 4)) * 1024);
    uint4* dlp = (uint4*)((unsigned char*)(ws + WS_DL) +
                          (((size_t)slice * 16 + kc) * 8 + (row >> 4)) * 1024);
#pragma unroll
    for (int qd = 0; qd < 4; qd++) {
      dhp[qd * 16 + r15] = make_uint4(hw[4 * qd], hw[4 * qd + 1], hw[4 * qd + 2], hw[4 * qd + 3]);
      dlp[qd * 16 + r15] = make_uint4(lw[4 * qd], lw[4 * qd + 1], lw[4 * qd + 2], lw[4 * qd + 3]);
    }
  }
  s += __shfl_xor(s, 1, 64);
  if (h2 == 0) ws[WS_D2 + gr] = (gr < NN) ? s : __builtin_inff();
}

/* ------- K2: GEMM core (NT=128, 256 thr); MODE 0 = sampled full top-10,
   MODE 1 = threshold filter. A-frags now come straight from L2 (frag-
   direct X image) — LDS holds only B. Halves LDS read BW per kc (16->8
   ds_read_b128/wave), which r3 counters identified as the binder
   (MfmaUtil 40% with HBM at 5%). Sync structure unchanged. -------------- */
struct StageT { unsigned char bh[8192], bl[8192]; };
struct EpiT  { float sq[64][132]; };
struct ListT { u64 kl[64][4][KNN]; };

template <int MODE> struct SmemSel {
  union U { StageT s; EpiT e; ListT l; };   /* MODE 0: 33792 B */
};
template <> struct SmemSel<1> {
  struct U { StageT s; u64 tau[128]; };     /* MODE 1: 17408 B */
};

/* r2 lesson: min-waves=5 caps VGPR at ~102 and spills the 64-AGPR
   accumulator (1.15 GB scratch traffic). Keep (256,3). */
template <int PRE, int MODE>
__global__ __launch_bounds__(256, 3) void knn_chunk(
    const float* __restrict__ dat, float* __restrict__ ws, int soff) {
  __shared__ __align__(16) typename SmemSel<MODE>::U sm;
  /* XCD-aware remap (MODE 1): cluster a slice's 8 qblocks onto one XCD
     (r3-verified: FETCH 374->58 MB). Bijective for gridDim.y % 8 == 0. */
  int bqx, bsy;
  if (MODE == 1 && (gridDim.y & 7) == 0) {
    const int n = (int)(blockIdx.y * gridDim.x + blockIdx.x);
    const int m = n >> 3;
    const int ypx = (int)(gridDim.y >> 3);
    bqx = m & 7;
    bsy = (n & 7) * ypx + (m >> 3);
  } else {
    bqx = blockIdx.x; bsy = blockIdx.y;
  }
  const int qbase = bqx * QTB;
  const int slice = bsy + soff;
  const int nbase = slice * NT;
  const int t = threadIdx.x;
  const int lane = t & 63, wave = t >> 6;
  const int wn = wave & 1, wq = wave >> 1;
  const unsigned char* dh = (const unsigned char*)(ws + WS_DH);
  const unsigned char* dl = (const unsigned char*)(ws + WS_DL);
  const char* xfh = (const char*)(ws + WS_XH);
  const char* xfl = (const char*)(ws + WS_XL);
  /* A-frag byte base: block ((bqx*8 + wq*4 + i)*16 + kc)*64 + lane */
  const int abase = (((bqx * 8 + wq * 4) * 16) * 64 + lane) * 16;

  f32x4 acc[4][4];
#pragma unroll
  for (int i = 0; i < 4; i++)
#pragma unroll
    for (int j = 0; j < 4; j++) acc[i][j] = (f32x4)0.f;

  auto stageB = [&](int kc) {
#pragma unroll
    for (int i = 0; i < 4; i++) {
      int pp = wave * 4 + i;
      int p = pp & 7;
      const unsigned char* g = (pp < 8 ? dh : dl) +
          (((size_t)slice * 16 + kc) * 8 + p) * 1024 + lane * 16;
      glds16(g, (pp < 8 ? sm.s.bh : sm.s.bl) + p * 1024);
    }
  };

  if (PRE) {
    /* pipelined: DMA(kc+1) issued after frag reads, overlaps MFMA(kc) */
    stageB(0);
    for (int kc = 0; kc < 16; kc++) {
      /* A-frags straight from L2; no barrier dependency, latency overlaps
         the barrier wait below */
      short8 fah[4], fal[4];
#pragma unroll
      for (int i = 0; i < 4; i++) {
        int off = abase + (i * 1024 + kc * 64) * 16;
        fah[i] = *(const short8*)(xfh + off);
        fal[i] = *(const short8*)(xfl + off);
      }
      __syncthreads();                    /* DMA(kc) complete */
      const int fragoff = lane * 16;
      short8 fbh[4], fbl[4];
#pragma unroll
      for (int i = 0; i < 4; i++) {
        fbh[i] = *(const short8*)(sm.s.bh + (wn * 4 + i) * 1024 + fragoff);
        fbl[i] = *(const short8*)(sm.s.bl + (wn * 4 + i) * 1024 + fragoff);
      }
      __syncthreads();                    /* all waves done reading LDS */
      if (kc < 15) stageB(kc + 1);        /* overlaps the MFMAs below */
      /* 3 sweeps of 16: consecutive MFMAs never share an accumulator */
#pragma unroll
      for (int mt = 0; mt < 4; mt++)
#pragma unroll
        for (int nt = 0; nt < 4; nt++)
          acc[mt][nt] = __builtin_amdgcn_mfma_f32_16x16x32_bf16(fah[mt], fbh[nt], acc[mt][nt], 0, 0, 0);
#pragma unroll
      for (int mt = 0; mt < 4; mt++)
#pragma unroll
        for (int nt = 0; nt < 4; nt++)
          acc[mt][nt] = __builtin_amdgcn_mfma_f32_16x16x32_bf16(fah[mt], fbl[nt], acc[mt][nt], 0, 0, 0);
#pragma unroll
      for (int mt = 0; mt < 4; mt++)
#pragma unroll
        for (int nt = 0; nt < 4; nt++)
          acc[mt][nt] = __builtin_amdgcn_mfma_f32_16x16x32_bf16(fal[mt], fbh[nt], acc[mt][nt], 0, 0, 0);
    }
  } else {
    /* fallback: in-loop B conversion (no tiled image in workspace) */
    const int brow = t >> 1, bh_half = t & 1;
    const int bgr = nbase + brow;
    const int bpanel = (brow >> 4) * 1024;
    const int bchunk = (brow & 15) * 16;
    for (int kc = 0; kc < 16; kc++) {
      const int kk = kc * BK;
      short8 fah[4], fal[4];
#pragma unroll
      for (int i = 0; i < 4; i++) {
        int off = abase + (i * 1024 + kc * 64) * 16;
        fah[i] = *(const short8*)(xfh + off);
        fal[i] = *(const short8*)(xfl + off);
      }
      __syncthreads();
      {
        float4 v0 = make_float4(0.f, 0.f, 0.f, 0.f), v1 = v0, v2 = v0, v3 = v0;
        if (bgr < NN) {
          const float4* src = (const float4*)(dat + (size_t)bgr * DD + kk + bh_half * 16);
          v0 = src[0]; v1 = src[1]; v2 = src[2]; v3 = src[3];
        }
        unsigned hw[8], lw[8];
        cvt2(v0.x, v0.y, hw[0], lw[0]); cvt2(v0.z, v0.w, hw[1], lw[1]);
        cvt2(v1.x, v1.y, hw[2], lw[2]); cvt2(v1.z, v1.w, hw[3], lw[3]);
        cvt2(v2.x, v2.y, hw[4], lw[4]); cvt2(v2.z, v2.w, hw[5], lw[5]);
        cvt2(v3.x, v3.y, hw[6], lw[6]); cvt2(v3.z, v3.w, hw[7], lw[7]);
        unsigned char* bhp = sm.s.bh + bpanel;
        unsigned char* blp = sm.s.bl + bpanel;
        *(uint4*)(bhp + (2 * bh_half) * 256 + bchunk)     = make_uint4(hw[0], hw[1], hw[2], hw[3]);
        *(uint4*)(bhp + (2 * bh_half + 1) * 256 + bchunk) = make_uint4(hw[4], hw[5], hw[6], hw[7]);
        *(uint4*)(blp + (2 * bh_half) * 256 + bchunk)     = make_uint4(lw[0], lw[1], lw[2], lw[3]);
        *(uint4*)(blp + (2 * bh_half + 1) * 256 + bchunk) = make_uint4(lw[4], lw[5], lw[6], lw[7]);
      }
      __syncthreads();
      const int fragoff = lane * 16;
      short8 fbh[4], fbl[4];
#pragma unroll
      for (int i = 0; i < 4; i++) {
        fbh[i] = *(const short8*)(sm.s.bh + (wn * 4 + i) * 1024 + fragoff);
        fbl[i] = *(const short8*)(sm.s.bl + (wn * 4 + i) * 1024 + fragoff);
      }
      __syncthreads();
#pragma unroll
      for (int mt = 0; mt < 4; mt++)
#pragma unroll
        for (int nt = 0; nt < 4; nt++) {
          acc[mt][nt] = __builtin_amdgcn_mfma_f32_16x16x32_bf16(fah[mt], fbh[nt], acc[mt][nt], 0, 0, 0);
          acc[mt][nt] = __builtin_amdgcn_mfma_f32_16x16x32_bf16(fah[mt], fbl[nt], acc[mt][nt], 0, 0, 0);
          acc[mt][nt] = __builtin_amdgcn_mfma_f32_16x16x32_bf16(fal[mt], fbh[nt], acc[mt][nt], 0, 0, 0);
        }
    }
  }

  if constexpr (MODE == 0) {
#pragma unroll
    for (int pass = 0; pass < 2; pass++) {
      __syncthreads();
      if (wq == pass) {
#pragma unroll
        for (int nt = 0; nt < 4; nt++) {
          int col = wn * 64 + nt * 16 + (lane & 15);
          float d2v = ws[WS_D2 + nbase + col];
#pragma unroll
          for (int mt = 0; mt < 4; mt++)
#pragma unroll
            for (int rg = 0; rg < 4; rg++) {
              int lr = mt * 16 + (lane >> 4) * 4 + rg;
              sm.e.sq[lr][col] = fmaf(-2.f, acc[mt][nt][rg], d2v);
            }
        }
      }
      __syncthreads();
      {
        const int r = t >> 2, s = t & 3;
        u64 kl[KNN];
#pragma unroll
        for (int u = 0; u < KNN; u++) kl[u] = ~0ull;
        for (int jj = 0; jj < 32; jj++) {
          int c = s * 32 + ((jj + r + 8 * s) & 31);
          float v = sm.e.sq[r][c];
          ins10(kl, mkkey(v, nbase + c));
        }
        __syncthreads();
#pragma unroll
        for (int u = 0; u < KNN; u++) sm.l.kl[r][s][u] = kl[u];
      }
      __syncthreads();
      if (t < 64) {
        u64* dst = ((u64*)(ws + WS_CKS)) +
                   ((size_t)(qbase + pass * 64 + t) * NSAMP + blockIdx.y) * KNN;
        int h0 = 0, h1 = 0, h2 = 0, h3 = 0;
        for (int pick = 0; pick < KNN; pick++) {
          u64 k0 = sm.l.kl[t][0][h0], k1 = sm.l.kl[t][1][h1];
          u64 k2 = sm.l.kl[t][2][h2], k3 = sm.l.kl[t][3][h3];
          u64 best = k0; int bm = 0;
          if (k1 < best) { best = k1; bm = 1; }
          if (k2 < best) { best = k2; bm = 2; }
          if (k3 < best) { best = k3; bm = 3; }
          dst[pick] = best;
          h0 += (bm == 0); h1 += (bm == 1); h2 += (bm == 2); h3 += (bm == 3);
        }
      }
    }
  } else {
    /* tau in its own LDS buffer (no stage-buffer aliasing). All waves are
       past the last K-step's second barrier; tau region untouched before
       here, so write -> barrier -> read is sufficient. */
    if (t < 128) sm.tau[t] = ((const u64*)(ws + WS_TAU))[qbase + t];
    __syncthreads();
    unsigned* cnt = (unsigned*)(ws + WS_CNT);
    u64* buf = (u64*)(ws + WS_BUF);
    float d2v[4];
#pragma unroll
    for (int nt = 0; nt < 4; nt++)
      d2v[nt] = ws[WS_D2 + nbase + wn * 64 + nt * 16 + (lane & 15)];
#pragma unroll
    for (int mt = 0; mt < 4; mt++)
#pragma unroll
      for (int rg = 0; rg < 4; rg++) {
        int row = wq * 64 + mt * 16 + (lane >> 4) * 4 + rg;
        u64 tr = sm.tau[row];
#pragma unroll
        for (int nt = 0; nt < 4; nt++) {
          float d = fmaf(-2.f, acc[mt][nt][rg], d2v[nt]);
          int col = nbase + wn * 64 + nt * 16 + (lane & 15);
          u64 key = mkkey(d, col);
          if (key < tr) {
            int q = qbase + row;
            unsigned slot = atomicAdd(cnt + q, 1u);
            if (slot < CAP) buf[(size_t)q * CAP + slot] = key;
          }
        }
      }
  }
}

/* ---------------- K2t: per-query tau = 10th of sampled keys ------------ */
__global__ __launch_bounds__(64) void tau_kernel(float* __restrict__ ws) {
  const int q = blockIdx.x;
  const int t = threadIdx.x;
  const u64* samp = ((const u64*)(ws + WS_CKS)) + (size_t)q * NSAMP * KNN;
  const int NC = NSAMP * KNN;
  u64 kl[KNN];
#pragma unroll
  for (int u = 0; u < KNN; u++) kl[u] = ~0ull;
  for (int j = t; j < NC; j += 64) ins10(kl, samp[j]);
  __shared__ u64 wk[64][KNN];
  __shared__ u64 m2[8][KNN];
#pragma unroll
  for (int u = 0; u < KNN; u++) wk[t][u] = kl[u];
  __syncthreads();
  if (t < 8) {
    int h[8] = {0, 0, 0, 0, 0, 0, 0, 0};
    for (int pick = 0; pick < KNN; pick++) {
      u64 best = ~0ull; int bm = 0;
#pragma unroll
      for (int m = 0; m < 8; m++) {
        u64 km = wk[t * 8 + m][h[m]];
        if (km < best) { best = km; bm = m; }
      }
      m2[t][pick] = best;
#pragma unroll
      for (int m = 0; m < 8; m++) h[m] += (bm == m);
    }
  }
  __syncthreads();
  if (t == 0) {
    int h[8] = {0, 0, 0, 0, 0, 0, 0, 0};
    u64 best = 0;
    for (int pick = 0; pick < KNN; pick++) {
      best = ~0ull; int bm = 0;
#pragma unroll
      for (int m = 0; m < 8; m++) {
        u64 km = m2[m][h[m]];
        if (km < best) { best = km; bm = m; }
      }
#pragma unroll
      for (int m = 0; m < 8; m++) h[m] += (bm == m);
    }
    ((u64*)(ws + WS_TAU))[q] = best;
    ((unsigned*)(ws + WS_CNT))[q] = 0u;
  }
}

/* ---------------- K3: final top-10 (sampled + survivors) + mode -------- */
__global__ __launch_bounds__(64) void knn_final(
    const int* __restrict__ targets, float* __restrict__ ws,
    float* __restrict__ out) {
  const int q = blockIdx.x;
  const int t = threadIdx.x;
  const u64* samp = ((const u64*)(ws + WS_CKS)) + (size_t)q * NSAMP * KNN;
  const u64* buf = ((const u64*)(ws + WS_BUF)) + (size_t)q * CAP;
  unsigned c = ((const unsigned*)(ws + WS_CNT))[q];
  if (c > CAP) c = CAP;

  u64 kl[KNN];
#pragma unroll
  for (int u = 0; u < KNN; u++) kl[u] = ~0ull;
  for (int j = t; j < NSAMP * KNN; j += 64) ins10(kl, samp[j]);
  for (int j = t; j < (int)c; j += 64) ins10(kl, buf[j]);

  __shared__ u64 wk[64][KNN];
  __shared__ u64 m2[8][KNN];
#pragma unroll
  for (int u = 0; u < KNN; u++) wk[t][u] = kl[u];
  __syncthreads();
  if (t < 8) {
    int h[8] = {0, 0, 0, 0, 0, 0, 0, 0};
    for (int pick = 0; pick < KNN; pick++) {
      u64 best = ~0ull; int bm = 0;
#pragma unroll
      for (int m = 0; m < 8; m++) {
        u64 km = wk[t * 8 + m][h[m]];
        if (km < best) { best = km; bm = m; }
      }
      m2[t][pick] = best;
#pragma unroll
      for (int m = 0; m < 8; m++) h[m] += (bm == m);
    }
  }
  __syncthreads();
  if (t == 0) {
    int h[8] = {0, 0, 0, 0, 0, 0, 0, 0};
    int fi[KNN];
    for (int pick = 0; pick < KNN; pick++) {
      u64 best = ~0ull; int bm = 0;
#pragma unroll
      for (int m = 0; m < 8; m++) {
        u64 km = m2[m][h[m]];
        if (km < best) { best = km; bm = m; }
      }
      fi[pick] = (int)(unsigned)(best & 0xffffffffu);
#pragma unroll
      for (int m = 0; m < 8; m++) h[m] += (bm == m);
    }
    int lab[KNN];
#pragma unroll
    for (int u = 0; u < KNN; u++) lab[u] = targets[fi[u]];
    int bc = 0, bl = INT_MAX;
#pragma unroll
    for (int i = 0; i < KNN; i++) {
      int cc = 0;
#pragma unroll
      for (int j = 0; j < KNN; j++) cc += (lab[j] == lab[i]) ? 1 : 0;
      if (cc > bc || (cc == bc && lab[i] < bl)) { bc = cc; bl = lab[i]; }
    }
    out[q] = (float)bl;
  }
}

extern "C" void kernel_launch(void* const* d_in, const int* in_sizes, int n_in,
                              void* d_out, int out_size, void* d_ws, size_t ws_size,
                              hipStream_t stream) {
  const float* Xm  = (const float*)d_in[0];
  const float* dat = (const float*)d_in[1];
  const int* targets = (const int*)d_in[2];
  float* out = (float*)d_out;
  float* ws  = (float*)d_ws;
  const bool pre = ws_size >= (size_t)WS_END * 4;   /* constant per process */

  hipLaunchKernelGGL(convx_kernel, dim3(QN * DD / 8 / 256), dim3(256), 0, stream, Xm, ws);
  hipLaunchKernelGGL(convd_kernel, dim3(NS), dim3(256), 0, stream, dat, ws);
  if (pre) {
    hipLaunchKernelGGL((knn_chunk<1, 0>), dim3(QB, NSAMP), dim3(256), 0, stream, dat, ws, 0);
    hipLaunchKernelGGL(tau_kernel, dim3(QN), dim3(64), 0, stream, ws);
    hipLaunchKernelGGL((knn_chunk<1, 1>), dim3(QB, NREST), dim3(256), 0, stream, dat, ws, NSAMP);
  } else {
    hipLaunchKernelGGL((knn_chunk<0, 0>), dim3(QB, NSAMP), dim3(256), 0, stream, dat, ws, 0);
    hipLaunchKernelGGL(tau_kernel, dim3(QN), dim3(64), 0, stream, ws);
    hipLaunchKernelGGL((knn_chunk<0, 1>), dim3(QB, NREST), dim3(256), 0, stream, dat, ws, NSAMP);
  }
  hipLaunchKernelGGL(knn_final, dim3(QN), dim3(64), 0, stream, targets, ws, out);
}

// Round 5
// 317.531 us; speedup vs baseline: 2.3155x; 1.1460x over previous
//
#include <hip/hip_runtime.h>
#include <math.h>
#include <limits.h>

#define QN 1024
#define NN 50000
#define NPAD 50048        /* 391*128 exactly */
#define DD 512
#define KNN 10
#define NT 128
#define QTB 128
#define BK 32
#define NS 391
#define QB 8
#define NSAMP 63
#define NREST (NS - NSAMP)    /* 328 = 8*41 -> XCD remap stays bijective */
#define CAP 512
#define SLACK 4.0f            /* hi-only d~ error: sigma~0.075 on d^2; 4.0 ~ 26 sigma */
#define LCAP 1152             /* >= NSAMP*KNN + CAP worst case (630+512) */

/* workspace layout, in 4-byte words */
#define WS_D2  0
#define WS_TAU 50048                       /* float[1024] (threshold, slacked) */
#define WS_CNT (WS_TAU + 1024)
#define WS_XH  (WS_CNT + 1024)
#define WS_CKS (WS_XH + QN * DD / 2)       /* u64[QN*NSAMP*KNN] */
#define WS_BUF (WS_CKS + QN * NSAMP * KNN * 2)
#define WS_DH  (WS_BUF + QN * CAP * 2)     /* tiled data hi: 391*16*8192 B */
#define WS_END (WS_DH + NS * 16 * 2048)

typedef __attribute__((ext_vector_type(8))) short short8;
typedef __attribute__((ext_vector_type(4))) float f32x4;
typedef unsigned long long u64;

__device__ __forceinline__ u64 mkkey(float f, int idx) {
  unsigned u = __float_as_uint(f);
  unsigned m = u ^ ((unsigned)((int)u >> 31) | 0x80000000u);
  return ((u64)m << 32) | (unsigned)idx;
}

/* decode the float from the hi-32 of a key */
__device__ __forceinline__ float keyhi_f(unsigned m) {
  unsigned u = (m & 0x80000000u) ? (m ^ 0x80000000u) : ~m;
  return __uint_as_float(u);
}

/* pack bf16(x),bf16(y) (round-to-nearest-even) into one u32 */
__device__ __forceinline__ unsigned cvth(float x, float y) {
  unsigned ux = __float_as_uint(x), uy = __float_as_uint(y);
  unsigned rx = ux + 0x7fffu + ((ux >> 16) & 1u);
  unsigned ry = uy + 0x7fffu + ((uy >> 16) & 1u);
  return (rx >> 16) | (ry & 0xffff0000u);
}

__device__ __forceinline__ void glds16(const void* g, void* l) {
  __builtin_amdgcn_global_load_lds(
      (const __attribute__((address_space(1))) unsigned*)g,
      (__attribute__((address_space(3))) unsigned*)l, 16, 0, 0);
}

__device__ __forceinline__ void ins10(u64* kl, u64 k) {
#pragma unroll
  for (int u = 0; u < KNN; u++) {
    u64 lo = (k < kl[u]) ? k : kl[u];
    u64 hi = (k < kl[u]) ? kl[u] : k;
    kl[u] = lo; k = hi;
  }
}

/* ---- K0 (fused): blockIdx < NS -> data preconvert (hi) + row norms;
        blockIdx >= NS -> X preconvert (hi, frag-direct layout). --------- */
__global__ __launch_bounds__(256) void conv_kernel(
    const float* __restrict__ dat, const float* __restrict__ Xm,
    float* __restrict__ ws) {
  if ((int)blockIdx.x >= NS) {
    /* convx part: frag-direct hi image. 16B block index
       g = (b*16 + kc)*64 + l; b=row>>4, kc=col/32, l=sub*16+(row&15). */
    const int g = ((int)blockIdx.x - NS) * 256 + threadIdx.x;  /* 0..65535 */
    const int b = g >> 10, kc = (g >> 6) & 15, l = g & 63;
    const int row = b * 16 + (l & 15);
    const int col = kc * 32 + (l >> 4) * 8;
    const float4* p = (const float4*)(Xm + (size_t)row * DD + col);
    float4 v0 = p[0], v1 = p[1];
    ((uint4*)(ws + WS_XH))[g] = make_uint4(
        cvth(v0.x, v0.y), cvth(v0.z, v0.w), cvth(v1.x, v1.y), cvth(v1.z, v1.w));
    return;
  }
  const int slice = blockIdx.x;
  const int t = threadIdx.x;
  const int row = t >> 1, h2 = t & 1;
  const int gr = slice * NT + row;
  const int r15 = row & 15;
  float s = 0.f;
#pragma unroll
  for (int kc8 = 0; kc8 < 8; kc8++) {
    const int kc = h2 * 8 + kc8;
    float4 v[8];
    if (gr < NN) {
      const float4* src = (const float4*)(dat + (size_t)gr * DD + kc * 32);
#pragma unroll
      for (int j = 0; j < 8; j++) v[j] = src[j];
    } else {
#pragma unroll
      for (int j = 0; j < 8; j++) v[j] = make_float4(0.f, 0.f, 0.f, 0.f);
    }
    unsigned hw[16];
#pragma unroll
    for (int j = 0; j < 8; j++) {
      s = fmaf(v[j].x, v[j].x, s); s = fmaf(v[j].y, v[j].y, s);
      s = fmaf(v[j].z, v[j].z, s); s = fmaf(v[j].w, v[j].w, s);
      hw[2 * j]     = cvth(v[j].x, v[j].y);
      hw[2 * j + 1] = cvth(v[j].z, v[j].w);
    }
    uint4* dhp = (uint4*)((unsigned char*)(ws + WS_DH) +
                          (((size_t)slice * 16 + kc) * 8 + (row >> 4)) * 1024);
#pragma unroll
    for (int qd = 0; qd < 4; qd++)
      dhp[qd * 16 + r15] = make_uint4(hw[4 * qd], hw[4 * qd + 1], hw[4 * qd + 2], hw[4 * qd + 3]);
  }
  s += __shfl_xor(s, 1, 64);
  if (h2 == 0) ws[WS_D2 + gr] = (gr < NN) ? s : __builtin_inff();
}

/* ------- K2: hi-only GEMM filter core (NT=128, 256 thr).
   MODE 0 = sampled per-slice top-10 of approx d~ (feeds tau);
   MODE 1 = threshold filter (d~ < tau+SLACK -> survivor buf).
   Exactness is restored later by knn_final's fp32 refine.
   A-frags from L2 (frag-direct X image), B staged hi-only via
   global_load_lds. Halves the L1 vector-path bytes r4 identified as the
   binder (48KB -> 24KB per block-kc). -------------------------------- */
struct StageT { unsigned char bh[8192]; };
struct EpiT  { float sq[64][132]; };
struct ListT { u64 kl[64][4][KNN]; };

template <int MODE> struct SmemSel {
  union U { StageT s; EpiT e; ListT l; };       /* MODE 0: 33792 B */
};
template <> struct SmemSel<1> {
  struct U { StageT s; float tau[128]; };       /* MODE 1: 8704 B */
};

/* r2 lesson: min-waves=5 caps VGPR at ~102 and spills the accumulator
   (1.15 GB scratch traffic). Keep (256,3). */
template <int PRE, int MODE>
__global__ __launch_bounds__(256, 3) void knn_chunk(
    const float* __restrict__ dat, float* __restrict__ ws, int soff) {
  __shared__ __align__(16) typename SmemSel<MODE>::U sm;
  /* XCD-aware remap (MODE 1): cluster a slice's 8 qblocks onto one XCD
     (r3-verified: FETCH 374->58 MB). Bijective for gridDim.y % 8 == 0. */
  int bqx, bsy;
  if (MODE == 1 && (gridDim.y & 7) == 0) {
    const int n = (int)(blockIdx.y * gridDim.x + blockIdx.x);
    const int m = n >> 3;
    const int ypx = (int)(gridDim.y >> 3);
    bqx = m & 7;
    bsy = (n & 7) * ypx + (m >> 3);
  } else {
    bqx = blockIdx.x; bsy = blockIdx.y;
  }
  const int qbase = bqx * QTB;
  const int slice = bsy + soff;
  const int nbase = slice * NT;
  const int t = threadIdx.x;
  const int lane = t & 63, wave = t >> 6;
  const int wn = wave & 1, wq = wave >> 1;
  const unsigned char* dh = (const unsigned char*)(ws + WS_DH);
  const char* xfh = (const char*)(ws + WS_XH);
  /* A-frag byte base: block ((bqx*8 + wq*4 + i)*16 + kc)*64 + lane */
  const int abase = (((bqx * 8 + wq * 4) * 16) * 64 + lane) * 16;

  f32x4 acc[4][4];
#pragma unroll
  for (int i = 0; i < 4; i++)
#pragma unroll
    for (int j = 0; j < 4; j++) acc[i][j] = (f32x4)0.f;

  auto stageB = [&](int kc) {
#pragma unroll
    for (int i = 0; i < 2; i++) {
      int p = wave * 2 + i;
      const unsigned char* g = dh +
          (((size_t)slice * 16 + kc) * 8 + p) * 1024 + lane * 16;
      glds16(g, sm.s.bh + p * 1024);
    }
  };

  if (PRE) {
    stageB(0);
    for (int kc = 0; kc < 16; kc++) {
      short8 fah[4];
#pragma unroll
      for (int i = 0; i < 4; i++)
        fah[i] = *(const short8*)(xfh + abase + i * 16384 + kc * 1024);
      __syncthreads();                    /* DMA(kc) complete */
      const int fragoff = lane * 16;
      short8 fbh[4];
#pragma unroll
      for (int i = 0; i < 4; i++)
        fbh[i] = *(const short8*)(sm.s.bh + (wn * 4 + i) * 1024 + fragoff);
      __syncthreads();                    /* all waves done reading LDS */
      if (kc < 15) stageB(kc + 1);        /* overlaps the MFMAs below */
#pragma unroll
      for (int mt = 0; mt < 4; mt++)
#pragma unroll
        for (int nt = 0; nt < 4; nt++)
          acc[mt][nt] = __builtin_amdgcn_mfma_f32_16x16x32_bf16(fah[mt], fbh[nt], acc[mt][nt], 0, 0, 0);
    }
  } else {
    /* fallback: in-loop B hi-conversion (no tiled image in workspace) */
    const int brow = t >> 1, bh_half = t & 1;
    const int bgr = nbase + brow;
    const int bpanel = (brow >> 4) * 1024;
    const int bchunk = (brow & 15) * 16;
    for (int kc = 0; kc < 16; kc++) {
      const int kk = kc * BK;
      short8 fah[4];
#pragma unroll
      for (int i = 0; i < 4; i++)
        fah[i] = *(const short8*)(xfh + abase + i * 16384 + kc * 1024);
      __syncthreads();
      {
        float4 v0 = make_float4(0.f, 0.f, 0.f, 0.f), v1 = v0, v2 = v0, v3 = v0;
        if (bgr < NN) {
          const float4* src = (const float4*)(dat + (size_t)bgr * DD + kk + bh_half * 16);
          v0 = src[0]; v1 = src[1]; v2 = src[2]; v3 = src[3];
        }
        unsigned char* bhp = sm.s.bh + bpanel;
        *(uint4*)(bhp + (2 * bh_half) * 256 + bchunk) =
            make_uint4(cvth(v0.x, v0.y), cvth(v0.z, v0.w), cvth(v1.x, v1.y), cvth(v1.z, v1.w));
        *(uint4*)(bhp + (2 * bh_half + 1) * 256 + bchunk) =
            make_uint4(cvth(v2.x, v2.y), cvth(v2.z, v2.w), cvth(v3.x, v3.y), cvth(v3.z, v3.w));
      }
      __syncthreads();
      const int fragoff = lane * 16;
      short8 fbh[4];
#pragma unroll
      for (int i = 0; i < 4; i++)
        fbh[i] = *(const short8*)(sm.s.bh + (wn * 4 + i) * 1024 + fragoff);
      __syncthreads();
#pragma unroll
      for (int mt = 0; mt < 4; mt++)
#pragma unroll
        for (int nt = 0; nt < 4; nt++)
          acc[mt][nt] = __builtin_amdgcn_mfma_f32_16x16x32_bf16(fah[mt], fbh[nt], acc[mt][nt], 0, 0, 0);
    }
  }

  if constexpr (MODE == 0) {
#pragma unroll
    for (int pass = 0; pass < 2; pass++) {
      __syncthreads();
      if (wq == pass) {
#pragma unroll
        for (int nt = 0; nt < 4; nt++) {
          int col = wn * 64 + nt * 16 + (lane & 15);
          float d2v = ws[WS_D2 + nbase + col];
#pragma unroll
          for (int mt = 0; mt < 4; mt++)
#pragma unroll
            for (int rg = 0; rg < 4; rg++) {
              int lr = mt * 16 + (lane >> 4) * 4 + rg;
              sm.e.sq[lr][col] = fmaf(-2.f, acc[mt][nt][rg], d2v);
            }
        }
      }
      __syncthreads();
      {
        const int r = t >> 2, s = t & 3;
        u64 kl[KNN];
#pragma unroll
        for (int u = 0; u < KNN; u++) kl[u] = ~0ull;
        for (int jj = 0; jj < 32; jj++) {
          int c = s * 32 + ((jj + r + 8 * s) & 31);
          float v = sm.e.sq[r][c];
          ins10(kl, mkkey(v, nbase + c));
        }
        __syncthreads();
#pragma unroll
        for (int u = 0; u < KNN; u++) sm.l.kl[r][s][u] = kl[u];
      }
      __syncthreads();
      if (t < 64) {
        u64* dst = ((u64*)(ws + WS_CKS)) +
                   ((size_t)(qbase + pass * 64 + t) * NSAMP + blockIdx.y) * KNN;
        int h0 = 0, h1 = 0, h2 = 0, h3 = 0;
        for (int pick = 0; pick < KNN; pick++) {
          u64 k0 = sm.l.kl[t][0][h0], k1 = sm.l.kl[t][1][h1];
          u64 k2 = sm.l.kl[t][2][h2], k3 = sm.l.kl[t][3][h3];
          u64 best = k0; int bm = 0;
          if (k1 < best) { best = k1; bm = 1; }
          if (k2 < best) { best = k2; bm = 2; }
          if (k3 < best) { best = k3; bm = 3; }
          dst[pick] = best;
          h0 += (bm == 0); h1 += (bm == 1); h2 += (bm == 2); h3 += (bm == 3);
        }
      }
    }
  } else {
    /* threshold filter: float compare against slacked tau */
    if (t < 128) sm.tau[t] = ws[WS_TAU + qbase + t];
    __syncthreads();
    unsigned* cnt = (unsigned*)(ws + WS_CNT);
    u64* buf = (u64*)(ws + WS_BUF);
    float d2v[4];
#pragma unroll
    for (int nt = 0; nt < 4; nt++)
      d2v[nt] = ws[WS_D2 + nbase + wn * 64 + nt * 16 + (lane & 15)];
#pragma unroll
    for (int mt = 0; mt < 4; mt++)
#pragma unroll
      for (int rg = 0; rg < 4; rg++) {
        int row = wq * 64 + mt * 16 + (lane >> 4) * 4 + rg;
        float tr = sm.tau[row];
#pragma unroll
        for (int nt = 0; nt < 4; nt++) {
          float d = fmaf(-2.f, acc[mt][nt][rg], d2v[nt]);
          if (d < tr) {
            int col = nbase + wn * 64 + nt * 16 + (lane & 15);
            int q = qbase + row;
            unsigned slot = atomicAdd(cnt + q, 1u);
            if (slot < CAP) buf[(size_t)q * CAP + slot] = mkkey(d, col);
          }
        }
      }
  }
}

/* ---------------- K2t: per-query tau = 10th of sampled keys + SLACK ---- */
__global__ __launch_bounds__(64) void tau_kernel(float* __restrict__ ws) {
  const int q = blockIdx.x;
  const int t = threadIdx.x;
  const u64* samp = ((const u64*)(ws + WS_CKS)) + (size_t)q * NSAMP * KNN;
  const int NC = NSAMP * KNN;
  u64 kl[KNN];
#pragma unroll
  for (int u = 0; u < KNN; u++) kl[u] = ~0ull;
  for (int j = t; j < NC; j += 64) ins10(kl, samp[j]);
  __shared__ u64 wk[64][KNN];
  __shared__ u64 m2[8][KNN];
#pragma unroll
  for (int u = 0; u < KNN; u++) wk[t][u] = kl[u];
  __syncthreads();
  if (t < 8) {
    int h[8] = {0, 0, 0, 0, 0, 0, 0, 0};
    for (int pick = 0; pick < KNN; pick++) {
      u64 best = ~0ull; int bm = 0;
#pragma unroll
      for (int m = 0; m < 8; m++) {
        u64 km = wk[t * 8 + m][h[m]];
        if (km < best) { best = km; bm = m; }
      }
      m2[t][pick] = best;
#pragma unroll
      for (int m = 0; m < 8; m++) h[m] += (bm == m);
    }
  }
  __syncthreads();
  if (t == 0) {
    int h[8] = {0, 0, 0, 0, 0, 0, 0, 0};
    u64 best = 0;
    for (int pick = 0; pick < KNN; pick++) {
      best = ~0ull; int bm = 0;
#pragma unroll
      for (int m = 0; m < 8; m++) {
        u64 km = m2[m][h[m]];
        if (km < best) { best = km; bm = m; }
      }
#pragma unroll
      for (int m = 0; m < 8; m++) h[m] += (bm == m);
    }
    ws[WS_TAU + q] = keyhi_f((unsigned)(best >> 32)) + SLACK;
    ((unsigned*)(ws + WS_CNT))[q] = 0u;
  }
}

/* ---------------- K3: candidate gather + exact fp32 refine + mode ------
   Candidates = {sampled keys with d~ < tau} U {survivors}. Slack math
   guarantees the exact top-10 is inside. Refine recomputes d exactly
   from raw dat (L3-resident), so final ordering matches the reference
   (up to fp32 rounding, strictly tighter than the old 3-sweep). ------- */
__global__ __launch_bounds__(256) void knn_final(
    const int* __restrict__ targets, const float* __restrict__ Xm,
    const float* __restrict__ dat, float* __restrict__ ws,
    float* __restrict__ out) {
  const int q = blockIdx.x;
  const int t = threadIdx.x;
  const int lane = t & 63, wave = t >> 6;
  __shared__ float qrow[DD];
  __shared__ unsigned lst[LCAP];
  __shared__ int nlist;
  __shared__ u64 wk4[4][KNN];
  if (t == 0) nlist = 0;
  if (t < 128) ((float4*)qrow)[t] = ((const float4*)(Xm + (size_t)q * DD))[t];
  __syncthreads();
  const float tr = ws[WS_TAU + q];
  const u64* samp = ((const u64*)(ws + WS_CKS)) + (size_t)q * NSAMP * KNN;
  for (int j = t; j < NSAMP * KNN; j += 256) {
    u64 k = samp[j];
    if (keyhi_f((unsigned)(k >> 32)) < tr) {
      int s_ = atomicAdd(&nlist, 1);
      if (s_ < LCAP) lst[s_] = (unsigned)k;
    }
  }
  unsigned c = ((const unsigned*)(ws + WS_CNT))[q];
  if (c > CAP) c = CAP;
  const u64* buf = ((const u64*)(ws + WS_BUF)) + (size_t)q * CAP;
  for (int j = t; j < (int)c; j += 256) {
    int s_ = atomicAdd(&nlist, 1);
    if (s_ < LCAP) lst[s_] = (unsigned)buf[j];
  }
  __syncthreads();
  const int n = nlist < LCAP ? nlist : LCAP;

  u64 kl[KNN];
#pragma unroll
  for (int u = 0; u < KNN; u++) kl[u] = ~0ull;
  const float4* qv = (const float4*)qrow;
  const float4 q0 = qv[lane * 2], q1 = qv[lane * 2 + 1];
  for (int j = wave; j < n; j += 4) {
    const unsigned idx = lst[j];
    const float4* xr = (const float4*)(dat + (size_t)idx * DD) + lane * 2;
    const float4 a0 = xr[0], a1 = xr[1];
    float p = a0.x * q0.x;
    p = fmaf(a0.y, q0.y, p); p = fmaf(a0.z, q0.z, p); p = fmaf(a0.w, q0.w, p);
    p = fmaf(a1.x, q1.x, p); p = fmaf(a1.y, q1.y, p);
    p = fmaf(a1.z, q1.z, p); p = fmaf(a1.w, q1.w, p);
#pragma unroll
    for (int s_ = 1; s_ < 64; s_ <<= 1) p += __shfl_xor(p, s_, 64);
    float d = fmaf(-2.f, p, ws[WS_D2 + idx]);
    ins10(kl, mkkey(d, (int)idx));
  }
  if (lane == 0)
#pragma unroll
    for (int u = 0; u < KNN; u++) wk4[wave][u] = kl[u];
  __syncthreads();
  if (t == 0) {
    int h[4] = {0, 0, 0, 0};
    int fi[KNN];
    for (int pick = 0; pick < KNN; pick++) {
      u64 best = ~0ull; int bm = 0;
#pragma unroll
      for (int m = 0; m < 4; m++) {
        u64 km = wk4[m][h[m]];
        if (km < best) { best = km; bm = m; }
      }
      fi[pick] = (int)(unsigned)(best & 0xffffffffu);
      h[bm]++;
    }
    int lab[KNN];
#pragma unroll
    for (int u = 0; u < KNN; u++) lab[u] = targets[fi[u]];
    int bc = 0, bl = INT_MAX;
#pragma unroll
    for (int i = 0; i < KNN; i++) {
      int cc = 0;
#pragma unroll
      for (int j = 0; j < KNN; j++) cc += (lab[j] == lab[i]) ? 1 : 0;
      if (cc > bc || (cc == bc && lab[i] < bl)) { bc = cc; bl = lab[i]; }
    }
    out[q] = (float)bl;
  }
}

extern "C" void kernel_launch(void* const* d_in, const int* in_sizes, int n_in,
                              void* d_out, int out_size, void* d_ws, size_t ws_size,
                              hipStream_t stream) {
  const float* Xm  = (const float*)d_in[0];
  const float* dat = (const float*)d_in[1];
  const int* targets = (const int*)d_in[2];
  float* out = (float*)d_out;
  float* ws  = (float*)d_ws;
  const bool pre = ws_size >= (size_t)WS_END * 4;   /* constant per process */

  hipLaunchKernelGGL(conv_kernel, dim3(NS + QN * DD / 8 / 256), dim3(256), 0,
                     stream, dat, Xm, ws);
  if (pre) {
    hipLaunchKernelGGL((knn_chunk<1, 0>), dim3(QB, NSAMP), dim3(256), 0, stream, dat, ws, 0);
    hipLaunchKernelGGL(tau_kernel, dim3(QN), dim3(64), 0, stream, ws);
    hipLaunchKernelGGL((knn_chunk<1, 1>), dim3(QB, NREST), dim3(256), 0, stream, dat, ws, NSAMP);
  } else {
    hipLaunchKernelGGL((knn_chunk<0, 0>), dim3(QB, NSAMP), dim3(256), 0, stream, dat, ws, 0);
    hipLaunchKernelGGL(tau_kernel, dim3(QN), dim3(64), 0, stream, ws);
    hipLaunchKernelGGL((knn_chunk<0, 1>), dim3(QB, NREST), dim3(256), 0, stream, dat, ws, NSAMP);
  }
  hipLaunchKernelGGL(knn_final, dim3(QN), dim3(256), 0, stream, targets, Xm, dat, ws, out);
}